// Round 8
// baseline (757.000 us; speedup 1.0000x reference)
//
#include <hip/hip_runtime.h>
#include <math.h>

#define BB 128
#define NN 256
#define EE 2048
#define BINS 16

typedef unsigned short u16;

// ---------------- CSR build, both sides: g in [0,2B) ----------------
__global__ void csr_kernel(const int* __restrict__ eq, const int* __restrict__ ec,
                           int* __restrict__ off, u16* __restrict__ srcs,
                           float* __restrict__ wts) {
    int g = blockIdx.x;                 // 0..2B-1
    int b = g < BB ? g : g - BB;
    const int* ei = g < BB ? eq : ec;
    int t = threadIdx.x;  // 256
    __shared__ int cnt[NN];
    __shared__ int sa[NN], sb[NN];
    __shared__ int cursor[NN];
    __shared__ float dvs[NN];
    cnt[t] = 0;
    __syncthreads();
    const int* src = ei + b * 2 * EE;
    const int* dst = src + EE;
    for (int e = t; e < EE; e += 256) atomicAdd(&cnt[dst[e]], 1);
    __syncthreads();
    dvs[t] = rsqrtf((float)cnt[t] + 1.0f);   // deg^-1/2 (incl self-loop)
    sa[t] = cnt[t];
    __syncthreads();
    int* pin = sa; int* pout = sb;
    for (int d = 1; d < NN; d <<= 1) {
        int v = pin[t];
        if (t >= d) v += pin[t - d];
        pout[t] = v;
        __syncthreads();
        int* tmp = pin; pin = pout; pout = tmp;
    }
    int excl = pin[t] - cnt[t];
    off[g * 257 + t] = excl;
    if (t == 255) off[g * 257 + 256] = EE;
    cursor[t] = excl;
    __syncthreads();
    for (int e = t; e < EE; e += 256) {
        int d = dst[e], s = src[e];
        int pos = atomicAdd(&cursor[d], 1);
        srcs[g * EE + pos] = (u16)s;
        wts[g * EE + pos] = dvs[s] * dvs[d];
    }
}

// ---------------- fully-fused 3-layer GCN: one graph per block (1024 thr) ----------------
// LDS: Hb[256][67]=68.6KB + xsT[16][260]=16.6KB + wts_s[16][64]=4KB + edges 13.3KB
//    ≈ 102.7KB -> 1 block/CU, 16 waves. Edges staged ONCE; X read once; O1/O2 never
//    leave the CU (a1/a2 in statically-indexed registers).
// GEMM body = round-0's proven 4x4 / stride-260 k-loop. Plain __launch_bounds__(1024)
// (min-waves clause caused VGPR=32 + spills in round 4).
__global__ __launch_bounds__(1024) void gcn_all(
        const float* __restrict__ XQ, const float* __restrict__ XC,
        const float* __restrict__ W1, const float* __restrict__ b1,
        const float* __restrict__ W2, const float* __restrict__ b2,
        const float* __restrict__ W3, const float* __restrict__ b3,
        const int* __restrict__ off, const u16* __restrict__ srcs,
        const float* __restrict__ wts, float* __restrict__ O3) {
    int g = blockIdx.x;
    int t = threadIdx.x;

    __shared__ float Hb[NN * 67];      // 68608 B (one 64-col half at a time)
    __shared__ float xsT[16 * 260];    // 16640 B, k-major [k][n]
    __shared__ float wts_s[16 * 64];   // 4096 B  [k][c]
    __shared__ int   eoff[NN + 1];
    __shared__ u16   esrc[EE];
    __shared__ float ewt[EE];

    const float* xg = (g < BB) ? (XQ + (size_t)g * NN * 128)
                               : (XC + (size_t)(g - BB) * NN * 128);
    // stage edges ONCE (overlaps L1 prologue)
    {
        const int* o = off + g * 257;
        const u16* sre = srcs + (size_t)g * EE;
        const float* wge = wts + (size_t)g * EE;
        for (int i = t; i < EE; i += 1024) { esrc[i] = sre[i]; ewt[i] = wge[i]; }
        if (t <= NN) eoff[t] = o[t];
    }

    int l = t & 63;               // GEMM: rows 4l..4l+3
    int wv = t >> 6;              // GEMM: wave -> col quad 4wv (0..60)
    int sr_ = t >> 2;             // X staging row
    int sq  = (t & 3) * 4;        // X staging k-quad
    int wr16 = t >> 6, wc64 = t & 63;   // W staging coords (16 rows x 64 cols)
    int gc = t & 63, gng = t >> 6;      // gather: channel 0..63, node group 0..15
    const float* xrow = xg + sr_ * 128 + sq;

    float a1[2][16];              // L1 activations (c = gc + 64*hf, nodes gng+16i)
    float a2[16];                 // L2 activations (c = gc, nodes gng+16i)

    // =================== L1: X @ W1, two 64-col halves ===================
#pragma unroll
    for (int hf = 0; hf < 2; ++hf) {
        const int cb = hf * 64;
        float acc[4][4];
#pragma unroll
        for (int i = 0; i < 4; i++)
#pragma unroll
            for (int j = 0; j < 4; j++) acc[i][j] = 0.f;
        float4 xv4 = *(const float4*)(xrow);
        float wreg = W1[(size_t)wr16 * 128 + cb + wc64];
        for (int k0 = 0; k0 < 128; k0 += 16) {
            xsT[(sq + 0) * 260 + sr_] = xv4.x;
            xsT[(sq + 1) * 260 + sr_] = xv4.y;
            xsT[(sq + 2) * 260 + sr_] = xv4.z;
            xsT[(sq + 3) * 260 + sr_] = xv4.w;
            wts_s[t] = wreg;
            __syncthreads();
            if (k0 + 16 < 128) {
                xv4 = *(const float4*)(xrow + k0 + 16);
                wreg = W1[(size_t)(k0 + 16 + wr16) * 128 + cb + wc64];
            }
#pragma unroll
            for (int k = 0; k < 16; k++) {
                float4 xv = *(const float4*)&xsT[k * 260 + 4 * l];
                float4 wvv = *(const float4*)&wts_s[k * 64 + 4 * wv];
                acc[0][0] += xv.x * wvv.x; acc[0][1] += xv.x * wvv.y;
                acc[0][2] += xv.x * wvv.z; acc[0][3] += xv.x * wvv.w;
                acc[1][0] += xv.y * wvv.x; acc[1][1] += xv.y * wvv.y;
                acc[1][2] += xv.y * wvv.z; acc[1][3] += xv.y * wvv.w;
                acc[2][0] += xv.z * wvv.x; acc[2][1] += xv.z * wvv.y;
                acc[2][2] += xv.z * wvv.z; acc[2][3] += xv.z * wvv.w;
                acc[3][0] += xv.w * wvv.x; acc[3][1] += xv.w * wvv.y;
                acc[3][2] += xv.w * wvv.z; acc[3][3] += xv.w * wvv.w;
            }
            __syncthreads();
        }
#pragma unroll
        for (int i = 0; i < 4; i++)
#pragma unroll
            for (int j = 0; j < 4; j++)
                Hb[(4 * l + i) * 67 + 4 * wv + j] = acc[i][j];
        __syncthreads();
        // gather (reads Hb; no trailing barrier — next phase's first barrier covers it)
        float bb_ = b1[cb + gc];
#pragma unroll
        for (int i = 0; i < 16; i++) {
            int n = gng + 16 * i;
            int j0 = eoff[n], j1 = eoff[n + 1];
            float a = 0.f;
            int j = j0;
            for (; j + 1 < j1; j += 2) {
                int s0 = esrc[j], s1 = esrc[j + 1];
                a += Hb[s0 * 67 + gc] * ewt[j];
                a += Hb[s1 * 67 + gc] * ewt[j + 1];
            }
            if (j < j1) a += Hb[esrc[j] * 67 + gc] * ewt[j];
            float d0i = 1.0f / ((float)(j1 - j0) + 1.0f);
            float v = a + Hb[n * 67 + gc] * d0i + bb_;
            a1[hf][i] = fmaxf(v, 0.f);
        }
    }

    // =================== L2: A1(regs) @ W2 -> Hb, gather -> a2 ===================
    {
        float acc[4][4];
#pragma unroll
        for (int i = 0; i < 4; i++)
#pragma unroll
            for (int j = 0; j < 4; j++) acc[i][j] = 0.f;
        float wreg = W2[(size_t)wr16 * 64 + wc64];
#pragma unroll
        for (int jt = 0; jt < 8; ++jt) {
            // stage A1 k-tile jt from registers: lanes owning channels [16*(jt&3), +16)
            if ((gc >> 4) == (jt & 3)) {
                int cr = gc - (jt & 3) * 16;
#pragma unroll
                for (int i = 0; i < 16; i++)
                    xsT[cr * 260 + gng + 16 * i] = (jt < 4) ? a1[0][i] : a1[1][i];
            }
            wts_s[t] = wreg;
            __syncthreads();
            if (jt + 1 < 8) wreg = W2[(size_t)((jt + 1) * 16 + wr16) * 64 + wc64];
#pragma unroll
            for (int k = 0; k < 16; k++) {
                float4 xv = *(const float4*)&xsT[k * 260 + 4 * l];
                float4 wvv = *(const float4*)&wts_s[k * 64 + 4 * wv];
                acc[0][0] += xv.x * wvv.x; acc[0][1] += xv.x * wvv.y;
                acc[0][2] += xv.x * wvv.z; acc[0][3] += xv.x * wvv.w;
                acc[1][0] += xv.y * wvv.x; acc[1][1] += xv.y * wvv.y;
                acc[1][2] += xv.y * wvv.z; acc[1][3] += xv.y * wvv.w;
                acc[2][0] += xv.z * wvv.x; acc[2][1] += xv.z * wvv.y;
                acc[2][2] += xv.z * wvv.z; acc[2][3] += xv.z * wvv.w;
                acc[3][0] += xv.w * wvv.x; acc[3][1] += xv.w * wvv.y;
                acc[3][2] += xv.w * wvv.z; acc[3][3] += xv.w * wvv.w;
            }
            __syncthreads();
        }
#pragma unroll
        for (int i = 0; i < 4; i++)
#pragma unroll
            for (int j = 0; j < 4; j++)
                Hb[(4 * l + i) * 67 + 4 * wv + j] = acc[i][j];
        __syncthreads();
        float bb_ = b2[gc];
#pragma unroll
        for (int i = 0; i < 16; i++) {
            int n = gng + 16 * i;
            int j0 = eoff[n], j1 = eoff[n + 1];
            float a = 0.f;
            int j = j0;
            for (; j + 1 < j1; j += 2) {
                int s0 = esrc[j], s1 = esrc[j + 1];
                a += Hb[s0 * 67 + gc] * ewt[j];
                a += Hb[s1 * 67 + gc] * ewt[j + 1];
            }
            if (j < j1) a += Hb[esrc[j] * 67 + gc] * ewt[j];
            float d0i = 1.0f / ((float)(j1 - j0) + 1.0f);
            float v = a + Hb[n * 67 + gc] * d0i + bb_;
            a2[i] = fmaxf(v, 0.f);
        }
    }

    // =================== L3: A2(regs) @ W3 -> Hb(32 cols), gather -> O3 ===================
    {
        float acc3[4][2];
#pragma unroll
        for (int i = 0; i < 4; i++) { acc3[i][0] = 0.f; acc3[i][1] = 0.f; }
        float wreg3 = (t < 512) ? W3[(size_t)(t >> 5) * 32 + (t & 31)] : 0.f;
#pragma unroll
        for (int jt = 0; jt < 4; ++jt) {
            if ((gc >> 4) == jt) {
                int cr = gc - jt * 16;
#pragma unroll
                for (int i = 0; i < 16; i++)
                    xsT[cr * 260 + gng + 16 * i] = a2[i];
            }
            if (t < 512) wts_s[t] = wreg3;
            __syncthreads();
            if (jt + 1 < 4 && t < 512)
                wreg3 = W3[(size_t)((jt + 1) * 16 + (t >> 5)) * 32 + (t & 31)];
#pragma unroll
            for (int k = 0; k < 16; k++) {
                float4 xv = *(const float4*)&xsT[k * 260 + 4 * l];
                float2 wvv = *(const float2*)&wts_s[k * 32 + 2 * wv];
                acc3[0][0] += xv.x * wvv.x; acc3[0][1] += xv.x * wvv.y;
                acc3[1][0] += xv.y * wvv.x; acc3[1][1] += xv.y * wvv.y;
                acc3[2][0] += xv.z * wvv.x; acc3[2][1] += xv.z * wvv.y;
                acc3[3][0] += xv.w * wvv.x; acc3[3][1] += xv.w * wvv.y;
            }
            __syncthreads();
        }
#pragma unroll
        for (int i = 0; i < 4; i++) {
            Hb[(4 * l + i) * 67 + 2 * wv + 0] = acc3[i][0];
            Hb[(4 * l + i) * 67 + 2 * wv + 1] = acc3[i][1];
        }
        __syncthreads();
        int c3 = t & 31, ng3 = t >> 5;    // 32 node groups of 8 nodes
        float bb_ = b3[c3];
        float* outp = O3 + (size_t)g * NN * 32;
#pragma unroll
        for (int i = 0; i < 8; i++) {
            int n = ng3 + 32 * i;
            int j0 = eoff[n], j1 = eoff[n + 1];
            float a = 0.f;
            int j = j0;
            for (; j + 1 < j1; j += 2) {
                int s0 = esrc[j], s1 = esrc[j + 1];
                a += Hb[s0 * 67 + c3] * ewt[j];
                a += Hb[s1 * 67 + c3] * ewt[j + 1];
            }
            if (j < j1) a += Hb[esrc[j] * 67 + c3] * ewt[j];
            float d0i = 1.0f / ((float)(j1 - j0) + 1.0f);
            outp[n * 32 + c3] = a + Hb[n * 67 + c3] * d0i + bb_;   // no ReLU on L3
        }
    }
}

// ---------------- attention pooling (both sides): one block per graph ----------------
__global__ void attpool_kernel(const float* __restrict__ X, const float* __restrict__ Watt,
                               float* __restrict__ e) {
    int g = blockIdx.x;   // 0..2B-1
    int t = threadIdx.x;
    __shared__ float xs[NN * 33];
    __shared__ float red[256];
    __shared__ float mean_s[32], ctx_s[32], sc[NN];
    const float* x = X + (size_t)g * NN * 32;
    for (int i = t; i < NN * 32; i += 256) { int n = i >> 5, c = i & 31; xs[n * 33 + c] = x[i]; }
    __syncthreads();
    {
        int c = t & 31, p = t >> 5;
        float s = 0.f;
        for (int n = p * 32; n < (p + 1) * 32; n++) s += xs[n * 33 + c];
        red[t] = s;
    }
    __syncthreads();
    if (t < 32) {
        float m = 0.f;
        for (int p = 0; p < 8; p++) m += red[p * 32 + t];
        mean_s[t] = m / (float)NN;
    }
    __syncthreads();
    if (t < 32) {
        float a = 0.f;
        for (int f = 0; f < 32; f++) a += mean_s[f] * Watt[t * 32 + f];
        ctx_s[t] = tanhf(a);
    }
    __syncthreads();
    {
        float a = 0.f;
        for (int f = 0; f < 32; f++) a += xs[t * 33 + f] * ctx_s[f];
        sc[t] = 1.f / (1.f + expf(-a));
    }
    __syncthreads();
    {
        int c = t & 31, p = t >> 5;
        float s = 0.f;
        for (int n = p * 32; n < (p + 1) * 32; n++) s += xs[n * 33 + c] * sc[n];
        red[t] = s;
    }
    __syncthreads();
    if (t < 32) {
        float s = 0.f;
        for (int p = 0; p < 8; p++) s += red[p * 32 + t];
        e[g * 32 + t] = s;
    }
}

// ---------------- pairwise dots: 128x128 tile, 8x8 per thread, f-major LDS ----------------
#define PD_STAGE_AND_DOT \
    int blk = blockIdx.x; \
    int b = blk >> 2; \
    int tq = (blk >> 1) & 1, tc = blk & 1; \
    __shared__ float qsT[32 * 132]; \
    __shared__ float csT[32 * 132]; \
    int t = threadIdx.x; \
    { \
        int n = t >> 1, f0 = (t & 1) * 16; \
        const float* qp = Q + ((size_t)b * NN + tq * 128 + n) * 32 + f0; \
        const float* cp = C + ((size_t)b * NN + tc * 128 + n) * 32 + f0; \
        float qa16[16], ca16[16]; \
        *(float4*)&qa16[0]  = *(const float4*)(qp); \
        *(float4*)&qa16[4]  = *(const float4*)(qp + 4); \
        *(float4*)&qa16[8]  = *(const float4*)(qp + 8); \
        *(float4*)&qa16[12] = *(const float4*)(qp + 12); \
        *(float4*)&ca16[0]  = *(const float4*)(cp); \
        *(float4*)&ca16[4]  = *(const float4*)(cp + 4); \
        *(float4*)&ca16[8]  = *(const float4*)(cp + 8); \
        *(float4*)&ca16[12] = *(const float4*)(cp + 12); \
        _Pragma("unroll") \
        for (int m = 0; m < 16; m++) { \
            qsT[(f0 + m) * 132 + n] = qa16[m]; \
            csT[(f0 + m) * 132 + n] = ca16[m]; \
        } \
    } \
    __syncthreads(); \
    int rg = (t >> 4) * 4, cg = (t & 15) * 4; \
    float acc[8][8]; \
    _Pragma("unroll") \
    for (int i = 0; i < 8; i++) \
        _Pragma("unroll") \
        for (int j = 0; j < 8; j++) acc[i][j] = 0.f; \
    _Pragma("unroll 2") \
    for (int f = 0; f < 32; f++) { \
        float4 qa = *(const float4*)&qsT[f * 132 + rg]; \
        float4 qb = *(const float4*)&qsT[f * 132 + 64 + rg]; \
        float4 ca = *(const float4*)&csT[f * 132 + cg]; \
        float4 cb = *(const float4*)&csT[f * 132 + 64 + cg]; \
        float qv[8] = {qa.x, qa.y, qa.z, qa.w, qb.x, qb.y, qb.z, qb.w}; \
        float cv[8] = {ca.x, ca.y, ca.z, ca.w, cb.x, cb.y, cb.z, cb.w}; \
        _Pragma("unroll") \
        for (int i = 0; i < 8; i++) \
            _Pragma("unroll") \
            for (int j = 0; j < 8; j++) acc[i][j] += qv[i] * cv[j]; \
    }

__global__ __launch_bounds__(256, 4) void pairdot_minmax(
        const float* __restrict__ Q, const float* __restrict__ C,
        float* __restrict__ bmin, float* __restrict__ bmax) {
    PD_STAGE_AND_DOT
    float lmin = acc[0][0], lmax = acc[0][0];
#pragma unroll
    for (int i = 0; i < 8; i++)
#pragma unroll
        for (int j = 0; j < 8; j++) {
            lmin = fminf(lmin, acc[i][j]);
            lmax = fmaxf(lmax, acc[i][j]);
        }
    __shared__ float rmin[256], rmax[256];
    rmin[t] = lmin; rmax[t] = lmax;
    __syncthreads();
    for (int s = 128; s > 0; s >>= 1) {
        if (t < s) { rmin[t] = fminf(rmin[t], rmin[t + s]); rmax[t] = fmaxf(rmax[t], rmax[t + s]); }
        __syncthreads();
    }
    if (t == 0) { bmin[blk] = rmin[0]; bmax[blk] = rmax[0]; }
}

// ---------------- global min/max reduce (1 block) + zero counts ----------------
__global__ void minmax_kernel(const float* __restrict__ bmin, const float* __restrict__ bmax,
                              float* __restrict__ lohi, float* __restrict__ counts) {
    __shared__ float rmin[256], rmax[256];
    int t = threadIdx.x;
    float lmin = 1e30f, lmax = -1e30f;
    for (int i = t; i < 512; i += 256) { lmin = fminf(lmin, bmin[i]); lmax = fmaxf(lmax, bmax[i]); }
    rmin[t] = lmin; rmax[t] = lmax;
    __syncthreads();
    for (int s = 128; s > 0; s >>= 1) {
        if (t < s) { rmin[t] = fminf(rmin[t], rmin[t + s]); rmax[t] = fmaxf(rmax[t], rmax[t + s]); }
        __syncthreads();
    }
    if (t == 0) { lohi[0] = rmin[0]; lohi[1] = rmax[0]; }
    if (t < BINS) counts[t] = 0.f;
}

// ---------------- pass 2: recompute dots, bit-sliced ballot histogram ----------------
__global__ __launch_bounds__(256, 4) void pairdot_hist(
        const float* __restrict__ Q, const float* __restrict__ C,
        const float* __restrict__ lohi, float* __restrict__ counts) {
    PD_STAGE_AND_DOT
    float lo = lohi[0], hi = lohi[1];
    float scale = (float)BINS / (hi - lo);
    int lane = t & 63;
    int cnt = 0;   // lane L accumulates count for bin (L & 15)
#pragma unroll
    for (int i = 0; i < 8; i++)
#pragma unroll
        for (int j = 0; j < 8; j++) {
            int idx = (int)floorf((acc[i][j] - lo) * scale);
            idx = min(max(idx, 0), BINS - 1);
            unsigned long long b0 = __ballot((idx & 1) != 0);
            unsigned long long b1 = __ballot((idx & 2) != 0);
            unsigned long long b2 = __ballot((idx & 4) != 0);
            unsigned long long b3 = __ballot((idx & 8) != 0);
            unsigned long long msk = ((lane & 1) ? b0 : ~b0);
            msk &= ((lane & 2) ? b1 : ~b1);
            msk &= ((lane & 4) ? b2 : ~b2);
            msk &= ((lane & 8) ? b3 : ~b3);
            cnt += __popcll(msk);
        }
    __shared__ float wbins[4][BINS];
    int wave = t >> 6;
    if (lane < BINS) wbins[wave][lane] = (float)cnt;
    __syncthreads();
    if (t < BINS) {
        atomicAdd(&counts[t], wbins[0][t] + wbins[1][t] + wbins[2][t] + wbins[3][t]);
    }
}

// ---------------- NTN + histogram concat + fc1 + fc2 head ----------------
__global__ void final_kernel(const float* __restrict__ e1, const float* __restrict__ e2,
                             const float* __restrict__ ntnW, const float* __restrict__ ntnV,
                             const float* __restrict__ ntnb, const float* __restrict__ counts,
                             const float* __restrict__ fc1W, const float* __restrict__ fc1b,
                             const float* __restrict__ fc2W, const float* __restrict__ fc2b,
                             float* __restrict__ out) {
    int b = blockIdx.x;
    int t = threadIdx.x;
    __shared__ float a1[32], a2[32], red[256], z[32], u[16];
    if (t < 32) a1[t] = e1[b * 32 + t];
    else if (t < 64) a2[t - 32] = e2[b * 32 + t - 32];
    __syncthreads();
    int tt = t >> 4, g = t & 15;
    float p = 0.f;
#pragma unroll
    for (int ii = 0; ii < 2; ii++) {
        int i = g + 16 * ii;
        float d = 0.f;
        const float* wr = ntnW + (tt * 32 + i) * 32;
        for (int j = 0; j < 32; j++) d += wr[j] * a2[j];
        p += a1[i] * d;
    }
    red[t] = p;
    __syncthreads();
    if (t < 16) {
        float s = 0.f;
        for (int g2 = 0; g2 < 16; g2++) s += red[t * 16 + g2];
        float lin = ntnb[t];
        for (int i = 0; i < 32; i++) lin += ntnV[t * 64 + i] * a1[i];
        for (int i = 0; i < 32; i++) lin += ntnV[t * 64 + 32 + i] * a2[i];
        z[t] = fmaxf(s + lin, 0.f);
    } else if (t < 32) {
        float tot = 0.f;
        for (int i = 0; i < BINS; i++) tot += counts[i];
        z[t] = counts[t - 16] / tot;
    }
    __syncthreads();
    if (t < 16) {
        float a = fc1b[t];
        for (int i = 0; i < 32; i++) a += fc1W[t * 32 + i] * z[i];
        u[t] = fmaxf(a, 0.f);
    }
    __syncthreads();
    if (t == 0) {
        float a = fc2b[0];
        for (int i = 0; i < 16; i++) a += fc2W[i] * u[i];
        out[b] = 1.f / (1.f + expf(-a));
    }
}

extern "C" void kernel_launch(void* const* d_in, const int* in_sizes, int n_in,
                              void* d_out, int out_size, void* d_ws, size_t ws_size,
                              hipStream_t stream) {
    const float* xq   = (const float*)d_in[0];
    const float* xc   = (const float*)d_in[1];
    const int*   eq   = (const int*)d_in[2];
    const int*   ec   = (const int*)d_in[3];
    const float* W1   = (const float*)d_in[4];
    const float* b1   = (const float*)d_in[5];
    const float* W2   = (const float*)d_in[6];
    const float* b2   = (const float*)d_in[7];
    const float* W3   = (const float*)d_in[8];
    const float* b3   = (const float*)d_in[9];
    const float* Watt = (const float*)d_in[10];
    const float* ntnW = (const float*)d_in[11];
    const float* ntnV = (const float*)d_in[12];
    const float* ntnb = (const float*)d_in[13];
    const float* fc1W = (const float*)d_in[14];
    const float* fc1b = (const float*)d_in[15];
    const float* fc2W = (const float*)d_in[16];
    const float* fc2b = (const float*)d_in[17];
    float* out = (float*)d_out;
    float* ws  = (float*)d_ws;

    // ---- workspace layout (float indices) ----
    float* O3   = ws;                            // 2*B*N*32  = 2097152
    float* e12  = O3 + 2097152;                  // 8192
    float* bmin = e12 + 8192;                    // 2048 (512 used)
    float* bmax = bmin + 2048;                   // 2048 (512 used)
    float* lohi = bmax + 2048;                   // 2
    float* cntw = lohi + 2;                      // 16
    int*   off  = (int*)(ws + 2109504);          // 2B*257 = 65792 ints
    u16*   srcs = (u16*)(off + 65792);           // 2B*E u16 = 262144 float slots
    float* wts  = ws + 2437440;                  // 2B*E f32 = 524288

    float* O3Q = O3;
    float* O3C = O3 + (size_t)BB * NN * 32;
    float* e1w = e12;
    float* e2w = e12 + BB * 32;

    csr_kernel<<<2 * BB, 256, 0, stream>>>(eq, ec, off, srcs, wts);

    // fully-fused 3-layer GCN: one graph per block/CU, O1/O2 never hit HBM
    gcn_all<<<2 * BB, 1024, 0, stream>>>(xq, xc, W1, b1, W2, b2, W3, b3,
                                         off, srcs, wts, O3);

    attpool_kernel<<<2 * BB, 256, 0, stream>>>(O3, Watt, e12);

    pairdot_minmax<<<BB * 4, 256, 0, stream>>>(O3Q, O3C, bmin, bmax);
    minmax_kernel<<<1, 256, 0, stream>>>(bmin, bmax, lohi, cntw);
    pairdot_hist<<<BB * 4, 256, 0, stream>>>(O3Q, O3C, lohi, cntw);

    final_kernel<<<BB, 256, 0, stream>>>(e1w, e2w, ntnW, ntnV, ntnb, cntw,
                                         fc1W, fc1b, fc2W, fc2b, out);
}

// Round 9
// 333.582 us; speedup vs baseline: 2.2693x; 2.2693x over previous
//
#include <hip/hip_runtime.h>
#include <math.h>

#define BB 128
#define NN 256
#define EE 2048
#define BINS 16

typedef unsigned short u16;

// ---------------- CSR build, both sides: g in [0,2B) ----------------
__global__ void csr_kernel(const int* __restrict__ eq, const int* __restrict__ ec,
                           int* __restrict__ off, u16* __restrict__ srcs,
                           float* __restrict__ wts) {
    int g = blockIdx.x;                 // 0..2B-1
    int b = g < BB ? g : g - BB;
    const int* ei = g < BB ? eq : ec;
    int t = threadIdx.x;  // 256
    __shared__ int cnt[NN];
    __shared__ int sa[NN], sb[NN];
    __shared__ int cursor[NN];
    __shared__ float dvs[NN];
    cnt[t] = 0;
    __syncthreads();
    const int* src = ei + b * 2 * EE;
    const int* dst = src + EE;
    for (int e = t; e < EE; e += 256) atomicAdd(&cnt[dst[e]], 1);
    __syncthreads();
    dvs[t] = rsqrtf((float)cnt[t] + 1.0f);   // deg^-1/2 (incl self-loop)
    sa[t] = cnt[t];
    __syncthreads();
    int* pin = sa; int* pout = sb;
    for (int d = 1; d < NN; d <<= 1) {
        int v = pin[t];
        if (t >= d) v += pin[t - d];
        pout[t] = v;
        __syncthreads();
        int* tmp = pin; pin = pout; pout = tmp;
    }
    int excl = pin[t] - cnt[t];
    off[g * 257 + t] = excl;
    if (t == 255) off[g * 257 + 256] = EE;
    cursor[t] = excl;
    __syncthreads();
    for (int e = t; e < EE; e += 256) {
        int d = dst[e], s = src[e];
        int pos = atomicAdd(&cursor[d], 1);
        srcs[g * EE + pos] = (u16)s;
        wts[g * EE + pos] = dvs[s] * dvs[d];
    }
}

// ---------------- fused GCN layer: W staged ONCE, k-tile 32, depth-2 reg prefetch ----
// 512 thr, 4x4 acc (R0's proven FMA body), CHUNK=32 cols per block.
// LDS: uni = max(Xs[32][260], hT[256][33]) = 33.8KB + Ws[FIN][32] (16/8KB)
//      + edges 13.3KB  => 63.5KB (L1/L2) -> 2 blocks/CU, 16 waves.
// Barriers: 8 per block for FIN=128 (vs 16 in R0/R5); stretch = 512 FMA-instr.
// Plain __launch_bounds__(512): min-waves clause caused VGPR=32 + spills (R4);
// register-resident activations caused spills (R8) — neither is used here.
template<int FIN, int FOUT, bool RELU, int NSPLIT>
__global__ __launch_bounds__(512) void gcn_fused7(
        const float* __restrict__ X0, const float* __restrict__ X1,
        const float* __restrict__ W, const float* __restrict__ bias,
        const int* __restrict__ off, const u16* __restrict__ srcs,
        const float* __restrict__ wts, float* __restrict__ OUT) {
    constexpr int CHUNKS = FOUT / 32;
    constexpr int NT = FIN / 32;                  // k-tiles of 32
    constexpr int UNI = (32 * 260 > NN * 33) ? 32 * 260 : NN * 33;   // 8448 floats
    int blk = blockIdx.x;
    int g = blk % (2 * BB);
    int rest = blk / (2 * BB);
    int cb = (rest % CHUNKS) * 32;
    int half = rest / CHUNKS;                     // 0..NSPLIT-1
    int t = threadIdx.x;

    __shared__ float uni[UNI];                    // Xs[32][260] k-major / hT[256][33]
    __shared__ float Ws[FIN * 32];                // full W chunk, staged once
    __shared__ int   eoff[NN + 1];
    __shared__ u16   esrc[EE];
    __shared__ float ewt[EE];
    float* Xs = uni;
    float* hT = uni;

    const float* xg = (g < BB) ? (X0 + (size_t)g * NN * FIN)
                               : (X1 + (size_t)(g - BB) * NN * FIN);

    // stage edges (coalesced; completes well before the gather)
    {
        const int* o = off + g * 257;
        const u16* sre = srcs + (size_t)g * EE;
        const float* wge = wts + (size_t)g * EE;
        for (int i = t; i < EE; i += 512) { esrc[i] = sre[i]; ewt[i] = wge[i]; }
        for (int i = t; i <= NN; i += 512) eoff[i] = o[i];
    }
    // stage the FULL weight chunk once: FIN*32 floats
#pragma unroll
    for (int j = 0; j < FIN * 32 / 2048; ++j) {
        int i = (t + 512 * j) * 4;
        int k = i >> 5, c = i & 31;
        *(float4*)&Ws[i] = *(const float4*)&W[(size_t)k * FOUT + cb + c];
    }

    // X staging: thread t owns row r = t>>1, k-halfwindow q = (t&1)*16 of each tile
    int r = t >> 1, q = (t & 1) * 16;
    const float* xrow = xg + (size_t)r * FIN;
    float4 px[4];

#define LOADPX(k0) { _Pragma("unroll") \
    for (int j = 0; j < 4; ++j) px[j] = *(const float4*)(xrow + (k0) + q + 4 * j); }
#define WRITEPX() { _Pragma("unroll") \
    for (int j = 0; j < 4; ++j) { float4 v = px[j]; int m = q + 4 * j; \
        Xs[(m + 0) * 260 + r] = v.x; Xs[(m + 1) * 260 + r] = v.y; \
        Xs[(m + 2) * 260 + r] = v.z; Xs[(m + 3) * 260 + r] = v.w; } }

    int l = t & 63;        // rows 4l..4l+3
    int wv = t >> 6;       // cols 4wv..4wv+3
    float acc[4][4];
#pragma unroll
    for (int i = 0; i < 4; i++)
#pragma unroll
        for (int j = 0; j < 4; j++) acc[i][j] = 0.f;

    LOADPX(0);
    WRITEPX();
    if (NT > 1) LOADPX(32);        // issue tile-1 loads immediately (deep cover)
    __syncthreads();

#pragma unroll
    for (int tile = 0; tile < NT; ++tile) {
#pragma unroll
        for (int kk = 0; kk < 32; ++kk) {
            float4 xv  = *(const float4*)&Xs[kk * 260 + 4 * l];            // lane-varying b128
            float4 wvv = *(const float4*)&Ws[(tile * 32 + kk) * 32 + 4 * wv]; // wave-uniform bcast
            acc[0][0] += xv.x * wvv.x; acc[0][1] += xv.x * wvv.y;
            acc[0][2] += xv.x * wvv.z; acc[0][3] += xv.x * wvv.w;
            acc[1][0] += xv.y * wvv.x; acc[1][1] += xv.y * wvv.y;
            acc[1][2] += xv.y * wvv.z; acc[1][3] += xv.y * wvv.w;
            acc[2][0] += xv.z * wvv.x; acc[2][1] += xv.z * wvv.y;
            acc[2][2] += xv.z * wvv.z; acc[2][3] += xv.z * wvv.w;
            acc[3][0] += xv.w * wvv.x; acc[3][1] += xv.w * wvv.y;
            acc[3][2] += xv.w * wvv.z; acc[3][3] += xv.w * wvv.w;
        }
        __syncthreads();                       // all Xs reads of this tile done
        if (tile + 1 < NT) {
            WRITEPX();                         // stage tile+1 (regs -> LDS)
            if (tile + 2 < NT) LOADPX((tile + 2) * 32);   // issue tile+2 global loads
            __syncthreads();
        }
    }
#pragma unroll
    for (int i = 0; i < 4; i++)
#pragma unroll
        for (int j = 0; j < 4; j++)
            hT[(4 * l + i) * 33 + 4 * wv + j] = acc[i][j];
    __syncthreads();

    // CSR-gather aggregation (precomputed edge weights, R0-proven form)
    int c = t & 31, ng = t >> 5;
    float bb_ = bias[cb + c];
    float* outp = OUT + (size_t)g * NN * FOUT;
    constexpr int NSEG = NN / NSPLIT;
    int nlo = half * NSEG, nhi = nlo + NSEG;
    for (int n = nlo + ng; n < nhi; n += 16) {
        int j0 = eoff[n], j1 = eoff[n + 1];
        float a = 0.f;
        int j = j0;
        for (; j + 1 < j1; j += 2) {
            int s0 = esrc[j], s1 = esrc[j + 1];
            a += hT[s0 * 33 + c] * ewt[j];
            a += hT[s1 * 33 + c] * ewt[j + 1];
        }
        if (j < j1) a += hT[esrc[j] * 33 + c] * ewt[j];
        float d0i = 1.0f / ((float)(j1 - j0) + 1.0f);   // self-loop norm 1/deg
        float val = a + hT[n * 33 + c] * d0i + bb_;
        if (RELU) val = fmaxf(val, 0.f);
        outp[n * FOUT + cb + c] = val;
    }
#undef LOADPX
#undef WRITEPX
}

// ---------------- attention pooling (both sides): one block per graph ----------------
__global__ void attpool_kernel(const float* __restrict__ X, const float* __restrict__ Watt,
                               float* __restrict__ e) {
    int g = blockIdx.x;   // 0..2B-1
    int t = threadIdx.x;
    __shared__ float xs[NN * 33];
    __shared__ float red[256];
    __shared__ float mean_s[32], ctx_s[32], sc[NN];
    const float* x = X + (size_t)g * NN * 32;
    for (int i = t; i < NN * 32; i += 256) { int n = i >> 5, c = i & 31; xs[n * 33 + c] = x[i]; }
    __syncthreads();
    {
        int c = t & 31, p = t >> 5;
        float s = 0.f;
        for (int n = p * 32; n < (p + 1) * 32; n++) s += xs[n * 33 + c];
        red[t] = s;
    }
    __syncthreads();
    if (t < 32) {
        float m = 0.f;
        for (int p = 0; p < 8; p++) m += red[p * 32 + t];
        mean_s[t] = m / (float)NN;
    }
    __syncthreads();
    if (t < 32) {
        float a = 0.f;
        for (int f = 0; f < 32; f++) a += mean_s[f] * Watt[t * 32 + f];
        ctx_s[t] = tanhf(a);
    }
    __syncthreads();
    {
        float a = 0.f;
        for (int f = 0; f < 32; f++) a += xs[t * 33 + f] * ctx_s[f];
        sc[t] = 1.f / (1.f + expf(-a));
    }
    __syncthreads();
    {
        int c = t & 31, p = t >> 5;
        float s = 0.f;
        for (int n = p * 32; n < (p + 1) * 32; n++) s += xs[n * 33 + c] * sc[n];
        red[t] = s;
    }
    __syncthreads();
    if (t < 32) {
        float s = 0.f;
        for (int p = 0; p < 8; p++) s += red[p * 32 + t];
        e[g * 32 + t] = s;
    }
}

// ---------------- pairwise dots: 128x128 tile, 8x8 per thread, f-major LDS ----------------
#define PD_STAGE_AND_DOT \
    int blk = blockIdx.x; \
    int b = blk >> 2; \
    int tq = (blk >> 1) & 1, tc = blk & 1; \
    __shared__ float qsT[32 * 132]; \
    __shared__ float csT[32 * 132]; \
    int t = threadIdx.x; \
    { \
        int n = t >> 1, f0 = (t & 1) * 16; \
        const float* qp = Q + ((size_t)b * NN + tq * 128 + n) * 32 + f0; \
        const float* cp = C + ((size_t)b * NN + tc * 128 + n) * 32 + f0; \
        float qa16[16], ca16[16]; \
        *(float4*)&qa16[0]  = *(const float4*)(qp); \
        *(float4*)&qa16[4]  = *(const float4*)(qp + 4); \
        *(float4*)&qa16[8]  = *(const float4*)(qp + 8); \
        *(float4*)&qa16[12] = *(const float4*)(qp + 12); \
        *(float4*)&ca16[0]  = *(const float4*)(cp); \
        *(float4*)&ca16[4]  = *(const float4*)(cp + 4); \
        *(float4*)&ca16[8]  = *(const float4*)(cp + 8); \
        *(float4*)&ca16[12] = *(const float4*)(cp + 12); \
        _Pragma("unroll") \
        for (int m = 0; m < 16; m++) { \
            qsT[(f0 + m) * 132 + n] = qa16[m]; \
            csT[(f0 + m) * 132 + n] = ca16[m]; \
        } \
    } \
    __syncthreads(); \
    int rg = (t >> 4) * 4, cg = (t & 15) * 4; \
    float acc[8][8]; \
    _Pragma("unroll") \
    for (int i = 0; i < 8; i++) \
        _Pragma("unroll") \
        for (int j = 0; j < 8; j++) acc[i][j] = 0.f; \
    _Pragma("unroll 2") \
    for (int f = 0; f < 32; f++) { \
        float4 qa = *(const float4*)&qsT[f * 132 + rg]; \
        float4 qb = *(const float4*)&qsT[f * 132 + 64 + rg]; \
        float4 ca = *(const float4*)&csT[f * 132 + cg]; \
        float4 cb = *(const float4*)&csT[f * 132 + 64 + cg]; \
        float qv[8] = {qa.x, qa.y, qa.z, qa.w, qb.x, qb.y, qb.z, qb.w}; \
        float cv[8] = {ca.x, ca.y, ca.z, ca.w, cb.x, cb.y, cb.z, cb.w}; \
        _Pragma("unroll") \
        for (int i = 0; i < 8; i++) \
            _Pragma("unroll") \
            for (int j = 0; j < 8; j++) acc[i][j] += qv[i] * cv[j]; \
    }

__global__ __launch_bounds__(256, 4) void pairdot_minmax(
        const float* __restrict__ Q, const float* __restrict__ C,
        float* __restrict__ bmin, float* __restrict__ bmax) {
    PD_STAGE_AND_DOT
    float lmin = acc[0][0], lmax = acc[0][0];
#pragma unroll
    for (int i = 0; i < 8; i++)
#pragma unroll
        for (int j = 0; j < 8; j++) {
            lmin = fminf(lmin, acc[i][j]);
            lmax = fmaxf(lmax, acc[i][j]);
        }
    __shared__ float rmin[256], rmax[256];
    rmin[t] = lmin; rmax[t] = lmax;
    __syncthreads();
    for (int s = 128; s > 0; s >>= 1) {
        if (t < s) { rmin[t] = fminf(rmin[t], rmin[t + s]); rmax[t] = fmaxf(rmax[t], rmax[t + s]); }
        __syncthreads();
    }
    if (t == 0) { bmin[blk] = rmin[0]; bmax[blk] = rmax[0]; }
}

// ---------------- global min/max reduce (1 block) + zero counts ----------------
__global__ void minmax_kernel(const float* __restrict__ bmin, const float* __restrict__ bmax,
                              float* __restrict__ lohi, float* __restrict__ counts) {
    __shared__ float rmin[256], rmax[256];
    int t = threadIdx.x;
    float lmin = 1e30f, lmax = -1e30f;
    for (int i = t; i < 512; i += 256) { lmin = fminf(lmin, bmin[i]); lmax = fmaxf(lmax, bmax[i]); }
    rmin[t] = lmin; rmax[t] = lmax;
    __syncthreads();
    for (int s = 128; s > 0; s >>= 1) {
        if (t < s) { rmin[t] = fminf(rmin[t], rmin[t + s]); rmax[t] = fmaxf(rmax[t], rmax[t + s]); }
        __syncthreads();
    }
    if (t == 0) { lohi[0] = rmin[0]; lohi[1] = rmax[0]; }
    if (t < BINS) counts[t] = 0.f;
}

// ---------------- pass 2: recompute dots, bit-sliced ballot histogram ----------------
__global__ __launch_bounds__(256, 4) void pairdot_hist(
        const float* __restrict__ Q, const float* __restrict__ C,
        const float* __restrict__ lohi, float* __restrict__ counts) {
    PD_STAGE_AND_DOT
    float lo = lohi[0], hi = lohi[1];
    float scale = (float)BINS / (hi - lo);
    int lane = t & 63;
    int cnt = 0;   // lane L accumulates count for bin (L & 15)
#pragma unroll
    for (int i = 0; i < 8; i++)
#pragma unroll
        for (int j = 0; j < 8; j++) {
            int idx = (int)floorf((acc[i][j] - lo) * scale);
            idx = min(max(idx, 0), BINS - 1);
            unsigned long long b0 = __ballot((idx & 1) != 0);
            unsigned long long b1 = __ballot((idx & 2) != 0);
            unsigned long long b2 = __ballot((idx & 4) != 0);
            unsigned long long b3 = __ballot((idx & 8) != 0);
            unsigned long long msk = ((lane & 1) ? b0 : ~b0);
            msk &= ((lane & 2) ? b1 : ~b1);
            msk &= ((lane & 4) ? b2 : ~b2);
            msk &= ((lane & 8) ? b3 : ~b3);
            cnt += __popcll(msk);
        }
    __shared__ float wbins[4][BINS];
    int wave = t >> 6;
    if (lane < BINS) wbins[wave][lane] = (float)cnt;
    __syncthreads();
    if (t < BINS) {
        atomicAdd(&counts[t], wbins[0][t] + wbins[1][t] + wbins[2][t] + wbins[3][t]);
    }
}

// ---------------- NTN + histogram concat + fc1 + fc2 head ----------------
__global__ void final_kernel(const float* __restrict__ e1, const float* __restrict__ e2,
                             const float* __restrict__ ntnW, const float* __restrict__ ntnV,
                             const float* __restrict__ ntnb, const float* __restrict__ counts,
                             const float* __restrict__ fc1W, const float* __restrict__ fc1b,
                             const float* __restrict__ fc2W, const float* __restrict__ fc2b,
                             float* __restrict__ out) {
    int b = blockIdx.x;
    int t = threadIdx.x;
    __shared__ float a1[32], a2[32], red[256], z[32], u[16];
    if (t < 32) a1[t] = e1[b * 32 + t];
    else if (t < 64) a2[t - 32] = e2[b * 32 + t - 32];
    __syncthreads();
    int tt = t >> 4, g = t & 15;
    float p = 0.f;
#pragma unroll
    for (int ii = 0; ii < 2; ii++) {
        int i = g + 16 * ii;
        float d = 0.f;
        const float* wr = ntnW + (tt * 32 + i) * 32;
        for (int j = 0; j < 32; j++) d += wr[j] * a2[j];
        p += a1[i] * d;
    }
    red[t] = p;
    __syncthreads();
    if (t < 16) {
        float s = 0.f;
        for (int g2 = 0; g2 < 16; g2++) s += red[t * 16 + g2];
        float lin = ntnb[t];
        for (int i = 0; i < 32; i++) lin += ntnV[t * 64 + i] * a1[i];
        for (int i = 0; i < 32; i++) lin += ntnV[t * 64 + 32 + i] * a2[i];
        z[t] = fmaxf(s + lin, 0.f);
    } else if (t < 32) {
        float tot = 0.f;
        for (int i = 0; i < BINS; i++) tot += counts[i];
        z[t] = counts[t - 16] / tot;
    }
    __syncthreads();
    if (t < 16) {
        float a = fc1b[t];
        for (int i = 0; i < 32; i++) a += fc1W[t * 32 + i] * z[i];
        u[t] = fmaxf(a, 0.f);
    }
    __syncthreads();
    if (t == 0) {
        float a = fc2b[0];
        for (int i = 0; i < 16; i++) a += fc2W[i] * u[i];
        out[b] = 1.f / (1.f + expf(-a));
    }
}

extern "C" void kernel_launch(void* const* d_in, const int* in_sizes, int n_in,
                              void* d_out, int out_size, void* d_ws, size_t ws_size,
                              hipStream_t stream) {
    const float* xq   = (const float*)d_in[0];
    const float* xc   = (const float*)d_in[1];
    const int*   eq   = (const int*)d_in[2];
    const int*   ec   = (const int*)d_in[3];
    const float* W1   = (const float*)d_in[4];
    const float* b1   = (const float*)d_in[5];
    const float* W2   = (const float*)d_in[6];
    const float* b2   = (const float*)d_in[7];
    const float* W3   = (const float*)d_in[8];
    const float* b3   = (const float*)d_in[9];
    const float* Watt = (const float*)d_in[10];
    const float* ntnW = (const float*)d_in[11];
    const float* ntnV = (const float*)d_in[12];
    const float* ntnb = (const float*)d_in[13];
    const float* fc1W = (const float*)d_in[14];
    const float* fc1b = (const float*)d_in[15];
    const float* fc2W = (const float*)d_in[16];
    const float* fc2b = (const float*)d_in[17];
    float* out = (float*)d_out;
    float* ws  = (float*)d_ws;

    // ---- workspace layout (float indices), [2B] contiguous buffers ----
    float* O3   = ws;                            // 2*B*N*32  = 2097152
    float* e12  = O3 + 2097152;                  // 8192
    float* bmin = e12 + 8192;                    // 2048 (512 used)
    float* bmax = bmin + 2048;                   // 2048 (512 used)
    float* lohi = bmax + 2048;                   // 2
    float* cntw = lohi + 2;                      // 16
    int*   off  = (int*)(ws + 2109504);          // 2B*257 = 65792 ints
    u16*   srcs = (u16*)(off + 65792);           // 2B*E u16 = 262144 float slots
    float* wts  = ws + 2437440;                  // 2B*E f32 = 524288
    float* O1   = ws + 3223872;                  // 2*B*N*128 = 8388608
    float* O2   = O1 + 8388608;                  // 2*B*N*64  = 4194304

    float* O3Q = O3;
    float* O3C = O3 + (size_t)BB * NN * 32;
    float* e1w = e12;
    float* e2w = e12 + BB * 32;

    csr_kernel<<<2 * BB, 256, 0, stream>>>(eq, ec, off, srcs, wts);

    // L1: 4 chunks of 32 cols -> 1024 blocks (2/CU resident, 2 rounds)
    gcn_fused7<128, 128, true, 1><<<4 * 2 * BB, 512, 0, stream>>>(
        xq, xc, W1, b1, off, srcs, wts, O1);
    // L2: 2 chunks -> 512 blocks (2/CU, 1 round)
    gcn_fused7<128, 64, true, 1><<<2 * 2 * BB, 512, 0, stream>>>(
        O1, O1 + (size_t)BB * NN * 128, W2, b2, off, srcs, wts, O2);
    // L3: 1 chunk, NSPLIT=2 -> 512 blocks (2/CU, 1 round)
    gcn_fused7<64, 32, false, 2><<<2 * 2 * BB, 512, 0, stream>>>(
        O2, O2 + (size_t)BB * NN * 64, W3, b3, off, srcs, wts, O3);

    attpool_kernel<<<2 * BB, 256, 0, stream>>>(O3, Watt, e12);

    pairdot_minmax<<<BB * 4, 256, 0, stream>>>(O3Q, O3C, bmin, bmax);
    minmax_kernel<<<1, 256, 0, stream>>>(bmin, bmax, lohi, cntw);
    pairdot_hist<<<BB * 4, 256, 0, stream>>>(O3Q, O3C, lohi, cntw);

    final_kernel<<<BB, 256, 0, stream>>>(e1w, e2w, ntnW, ntnV, ntnb, cntw,
                                         fc1W, fc1b, fc2W, fc2b, out);
}

// Round 10
// 279.875 us; speedup vs baseline: 2.7048x; 1.1919x over previous
//
#include <hip/hip_runtime.h>
#include <math.h>

#define BB 128
#define NN 256
#define EE 2048
#define BINS 16

// monotone float <-> uint encoding for atomic min/max on floats
__device__ __forceinline__ unsigned int fenc(float f) {
    unsigned int u = __float_as_uint(f);
    return (u & 0x80000000u) ? ~u : (u | 0x80000000u);
}
__device__ __forceinline__ float fdec(unsigned int u) {
    return (u & 0x80000000u) ? __uint_as_float(u & 0x7FFFFFFFu)
                             : __uint_as_float(~u);
}

// ---------------- CSR build, both sides: g in [0,2B). Block 0 also inits
// the histogram accumulators (counts, encoded lo/hi) for this graph replay. ----
__global__ void csr_kernel(const int* __restrict__ eq, const int* __restrict__ ec,
                           int* __restrict__ off, int* __restrict__ srcs,
                           float* __restrict__ wts,
                           unsigned int* __restrict__ lohiE,
                           float* __restrict__ counts) {
    int g = blockIdx.x;                 // 0..2B-1
    int b = g < BB ? g : g - BB;
    const int* ei = g < BB ? eq : ec;
    int t = threadIdx.x;  // 256
    if (g == 0) {
        if (t < BINS) counts[t] = 0.f;
        if (t == 16) lohiE[0] = 0xFFFFFFFFu;   // min accumulator (encoded +inf)
        if (t == 17) lohiE[1] = 0u;            // max accumulator (encoded -inf)
    }
    __shared__ int cnt[NN];
    __shared__ int sa[NN], sb[NN];
    __shared__ int cursor[NN];
    __shared__ float dvs[NN];
    cnt[t] = 0;
    __syncthreads();
    const int* src = ei + b * 2 * EE;
    const int* dst = src + EE;
    for (int e = t; e < EE; e += 256) atomicAdd(&cnt[dst[e]], 1);
    __syncthreads();
    dvs[t] = rsqrtf((float)cnt[t] + 1.0f);
    sa[t] = cnt[t];
    __syncthreads();
    int* pin = sa; int* pout = sb;
    for (int d = 1; d < NN; d <<= 1) {
        int v = pin[t];
        if (t >= d) v += pin[t - d];
        pout[t] = v;
        __syncthreads();
        int* tmp = pin; pin = pout; pout = tmp;
    }
    int excl = pin[t] - cnt[t];
    off[g * 257 + t] = excl;
    if (t == 255) off[g * 257 + 256] = EE;
    cursor[t] = excl;
    __syncthreads();
    for (int e = t; e < EE; e += 256) {
        int d = dst[e], s = src[e];
        int pos = atomicAdd(&cursor[d], 1);
        srcs[g * EE + pos] = s;
        wts[g * EE + pos] = dvs[s] * dvs[d];
    }
}

// ---------------- fused GCN layer — round-0's proven 74.5µs configuration ----------------
// 512 thr, per-thread 4 rows x 4 cols, k-tile 16, separate hT, int esrc + LDS ewt.
// LDS ~70.1KB -> 2 blocks/CU. Plain __launch_bounds__(512) (min-waves forced VGPR=32
// + spills in R4; this config compiles to 64 VGPR, no spill — R0 measured).
// NSPLIT only splits the gather node-range (duplicate GEMM) to widen small layers' grids.
template<int FIN, int FOUT, bool RELU, int NSPLIT>
__global__ __launch_bounds__(512) void gcn_fused8(
        const float* __restrict__ X0, const float* __restrict__ X1,
        const float* __restrict__ W, const float* __restrict__ bias,
        const int* __restrict__ off, const int* __restrict__ srcs,
        const float* __restrict__ wts, float* __restrict__ OUT) {
    constexpr int CHUNKS = FOUT / 32;
    int blk = blockIdx.x;
    int g = blk % (2 * BB);
    int rest = blk / (2 * BB);
    int cb = (rest % CHUNKS) * 32;
    int half = rest / CHUNKS;          // 0..NSPLIT-1
    int t = threadIdx.x;

    __shared__ float hT[NN * 33];      // H chunk [n][c], stride 33
    __shared__ float xsT[16 * 260];    // X k-tile, k-major [k][n]
    __shared__ float wt[16 * 32];      // W k-tile [k][c]
    __shared__ int   eoff[NN + 1];
    __shared__ int   esrc[EE];
    __shared__ float ewt[EE];

    const float* xg = (g < BB) ? (X0 + (size_t)g * NN * FIN)
                               : (X1 + (size_t)(g - BB) * NN * FIN);
    const int* o = off + g * 257;
    const int* sr = srcs + (size_t)g * EE;
    const float* wg = wts + (size_t)g * EE;

    // stage edges + offsets (coalesced; completes during k-loop)
    for (int i = t; i < EE; i += 512) { esrc[i] = sr[i]; ewt[i] = wg[i]; }
    for (int i = t; i <= NN; i += 512) eoff[i] = o[i];

    int l = t & 63;        // lane -> node quad (rows 4l..4l+3)
    int wv = t >> 6;       // wave -> channel quad (cols 4wv..4wv+3)

    float acc[4][4];
#pragma unroll
    for (int i = 0; i < 4; i++)
#pragma unroll
        for (int j = 0; j < 4; j++) acc[i][j] = 0.f;

    int sn = t >> 1, qk = (t & 1) * 8;
    const float* xr = xg + sn * FIN + qk;
    float4 v0 = *(const float4*)xr;
    float4 v1 = *(const float4*)(xr + 4);
    float wreg = W[(t >> 5) * FOUT + cb + (t & 31)];

    for (int k0 = 0; k0 < FIN; k0 += 16) {
        xsT[(qk + 0) * 260 + sn] = v0.x;
        xsT[(qk + 1) * 260 + sn] = v0.y;
        xsT[(qk + 2) * 260 + sn] = v0.z;
        xsT[(qk + 3) * 260 + sn] = v0.w;
        xsT[(qk + 4) * 260 + sn] = v1.x;
        xsT[(qk + 5) * 260 + sn] = v1.y;
        xsT[(qk + 6) * 260 + sn] = v1.z;
        xsT[(qk + 7) * 260 + sn] = v1.w;
        wt[t] = wreg;
        __syncthreads();
        if (k0 + 16 < FIN) {
            xr += 16;
            v0 = *(const float4*)xr;
            v1 = *(const float4*)(xr + 4);
            wreg = W[(k0 + 16 + (t >> 5)) * FOUT + cb + (t & 31)];
        }
#pragma unroll
        for (int k = 0; k < 16; k++) {
            float4 xv = *(const float4*)&xsT[k * 260 + 4 * l];
            float4 wvv = *(const float4*)&wt[k * 32 + 4 * wv];
            acc[0][0] += xv.x * wvv.x; acc[0][1] += xv.x * wvv.y;
            acc[0][2] += xv.x * wvv.z; acc[0][3] += xv.x * wvv.w;
            acc[1][0] += xv.y * wvv.x; acc[1][1] += xv.y * wvv.y;
            acc[1][2] += xv.y * wvv.z; acc[1][3] += xv.y * wvv.w;
            acc[2][0] += xv.z * wvv.x; acc[2][1] += xv.z * wvv.y;
            acc[2][2] += xv.z * wvv.z; acc[2][3] += xv.z * wvv.w;
            acc[3][0] += xv.w * wvv.x; acc[3][1] += xv.w * wvv.y;
            acc[3][2] += xv.w * wvv.z; acc[3][3] += xv.w * wvv.w;
        }
        __syncthreads();
    }
#pragma unroll
    for (int i = 0; i < 4; i++)
#pragma unroll
        for (int j = 0; j < 4; j++)
            hT[(4 * l + i) * 33 + 4 * wv + j] = acc[i][j];
    __syncthreads();

    // CSR-gather aggregation: everything in LDS (R0's 1-deep pipelined form)
    int c = t & 31, ng = t >> 5;
    float bb_ = bias[cb + c];
    float* outp = OUT + (size_t)g * NN * FOUT;
    constexpr int NSEG = NN / NSPLIT;
    int nlo = half * NSEG, nhi = nlo + NSEG;
    for (int n = nlo + ng; n < nhi; n += 16) {
        int j0 = eoff[n], j1 = eoff[n + 1];
        float a = 0.f;
        int j = j0;
        if (j < j1) {
            int s0 = esrc[j];
            float w0 = ewt[j];
            for (++j; j < j1; ++j) {
                int s1 = esrc[j];
                float w1 = ewt[j];
                a += hT[s0 * 33 + c] * w0;
                s0 = s1; w0 = w1;
            }
            a += hT[s0 * 33 + c] * w0;
        }
        float d0 = rsqrtf((float)(j1 - j0) + 1.0f);
        float val = a + hT[n * 33 + c] * d0 * d0 + bb_;
        if (RELU) val = fmaxf(val, 0.f);
        outp[n * FOUT + cb + c] = val;
    }
}

// ---------------- attention pooling (both sides): one block per graph ----------------
__global__ void attpool_kernel(const float* __restrict__ X, const float* __restrict__ Watt,
                               float* __restrict__ e) {
    int g = blockIdx.x;   // 0..2B-1
    int t = threadIdx.x;
    __shared__ float xs[NN * 33];
    __shared__ float red[256];
    __shared__ float mean_s[32], ctx_s[32], sc[NN];
    const float* x = X + (size_t)g * NN * 32;
    for (int i = t; i < NN * 32; i += 256) { int n = i >> 5, c = i & 31; xs[n * 33 + c] = x[i]; }
    __syncthreads();
    {
        int c = t & 31, p = t >> 5;
        float s = 0.f;
        for (int n = p * 32; n < (p + 1) * 32; n++) s += xs[n * 33 + c];
        red[t] = s;
    }
    __syncthreads();
    if (t < 32) {
        float m = 0.f;
        for (int p = 0; p < 8; p++) m += red[p * 32 + t];
        mean_s[t] = m / (float)NN;
    }
    __syncthreads();
    if (t < 32) {
        float a = 0.f;
        for (int f = 0; f < 32; f++) a += mean_s[f] * Watt[t * 32 + f];
        ctx_s[t] = tanhf(a);
    }
    __syncthreads();
    {
        float a = 0.f;
        for (int f = 0; f < 32; f++) a += xs[t * 33 + f] * ctx_s[f];
        sc[t] = 1.f / (1.f + expf(-a));
    }
    __syncthreads();
    {
        int c = t & 31, p = t >> 5;
        float s = 0.f;
        for (int n = p * 32; n < (p + 1) * 32; n++) s += xs[n * 33 + c] * sc[n];
        red[t] = s;
    }
    __syncthreads();
    if (t < 32) {
        float s = 0.f;
        for (int p = 0; p < 8; p++) s += red[p * 32 + t];
        e[g * 32 + t] = s;
    }
}

// ---------------- pairwise dots: 128x128 tile, 8x8 per thread, f-major LDS ----------------
#define PD_STAGE_AND_DOT \
    int blk = blockIdx.x; \
    int b = blk >> 2; \
    int tq = (blk >> 1) & 1, tc = blk & 1; \
    __shared__ float qsT[32 * 132]; \
    __shared__ float csT[32 * 132]; \
    int t = threadIdx.x; \
    { \
        int n = t >> 1, f0 = (t & 1) * 16; \
        const float* qp = Q + ((size_t)b * NN + tq * 128 + n) * 32 + f0; \
        const float* cp = C + ((size_t)b * NN + tc * 128 + n) * 32 + f0; \
        float qa16[16], ca16[16]; \
        *(float4*)&qa16[0]  = *(const float4*)(qp); \
        *(float4*)&qa16[4]  = *(const float4*)(qp + 4); \
        *(float4*)&qa16[8]  = *(const float4*)(qp + 8); \
        *(float4*)&qa16[12] = *(const float4*)(qp + 12); \
        *(float4*)&ca16[0]  = *(const float4*)(cp); \
        *(float4*)&ca16[4]  = *(const float4*)(cp + 4); \
        *(float4*)&ca16[8]  = *(const float4*)(cp + 8); \
        *(float4*)&ca16[12] = *(const float4*)(cp + 12); \
        _Pragma("unroll") \
        for (int m = 0; m < 16; m++) { \
            qsT[(f0 + m) * 132 + n] = qa16[m]; \
            csT[(f0 + m) * 132 + n] = ca16[m]; \
        } \
    } \
    __syncthreads(); \
    int rg = (t >> 4) * 4, cg = (t & 15) * 4; \
    float acc[8][8]; \
    _Pragma("unroll") \
    for (int i = 0; i < 8; i++) \
        _Pragma("unroll") \
        for (int j = 0; j < 8; j++) acc[i][j] = 0.f; \
    _Pragma("unroll 2") \
    for (int f = 0; f < 32; f++) { \
        float4 qa = *(const float4*)&qsT[f * 132 + rg]; \
        float4 qb = *(const float4*)&qsT[f * 132 + 64 + rg]; \
        float4 ca = *(const float4*)&csT[f * 132 + cg]; \
        float4 cb = *(const float4*)&csT[f * 132 + 64 + cg]; \
        float qv[8] = {qa.x, qa.y, qa.z, qa.w, qb.x, qb.y, qb.z, qb.w}; \
        float cv[8] = {ca.x, ca.y, ca.z, ca.w, cb.x, cb.y, cb.z, cb.w}; \
        _Pragma("unroll") \
        for (int i = 0; i < 8; i++) \
            _Pragma("unroll") \
            for (int j = 0; j < 8; j++) acc[i][j] += qv[i] * cv[j]; \
    }

// pass 1: min/max -> device atomics on encoded uints (replaces minmax_kernel launch)
__global__ __launch_bounds__(256, 4) void pairdot_minmax(
        const float* __restrict__ Q, const float* __restrict__ C,
        unsigned int* __restrict__ lohiE) {
    PD_STAGE_AND_DOT
    float lmin = acc[0][0], lmax = acc[0][0];
#pragma unroll
    for (int i = 0; i < 8; i++)
#pragma unroll
        for (int j = 0; j < 8; j++) {
            lmin = fminf(lmin, acc[i][j]);
            lmax = fmaxf(lmax, acc[i][j]);
        }
    __shared__ float rmin[256], rmax[256];
    rmin[t] = lmin; rmax[t] = lmax;
    __syncthreads();
    for (int s = 128; s > 0; s >>= 1) {
        if (t < s) { rmin[t] = fminf(rmin[t], rmin[t + s]); rmax[t] = fmaxf(rmax[t], rmax[t + s]); }
        __syncthreads();
    }
    if (t == 0) {
        atomicMin(&lohiE[0], fenc(rmin[0]));
        atomicMax(&lohiE[1], fenc(rmax[0]));
    }
}

// pass 2: recompute dots, bit-sliced ballot histogram
__global__ __launch_bounds__(256, 4) void pairdot_hist(
        const float* __restrict__ Q, const float* __restrict__ C,
        const unsigned int* __restrict__ lohiE, float* __restrict__ counts) {
    PD_STAGE_AND_DOT
    float lo = fdec(lohiE[0]), hi = fdec(lohiE[1]);
    float scale = (float)BINS / (hi - lo);
    int lane = t & 63;
    int cnt = 0;   // lane L accumulates count for bin (L & 15)
#pragma unroll
    for (int i = 0; i < 8; i++)
#pragma unroll
        for (int j = 0; j < 8; j++) {
            int idx = (int)floorf((acc[i][j] - lo) * scale);
            idx = min(max(idx, 0), BINS - 1);
            unsigned long long b0 = __ballot((idx & 1) != 0);
            unsigned long long b1 = __ballot((idx & 2) != 0);
            unsigned long long b2 = __ballot((idx & 4) != 0);
            unsigned long long b3 = __ballot((idx & 8) != 0);
            unsigned long long msk = ((lane & 1) ? b0 : ~b0);
            msk &= ((lane & 2) ? b1 : ~b1);
            msk &= ((lane & 4) ? b2 : ~b2);
            msk &= ((lane & 8) ? b3 : ~b3);
            cnt += __popcll(msk);
        }
    __shared__ float wbins[4][BINS];
    int wave = t >> 6;
    if (lane < BINS) wbins[wave][lane] = (float)cnt;
    __syncthreads();
    if (t < BINS) {
        atomicAdd(&counts[t], wbins[0][t] + wbins[1][t] + wbins[2][t] + wbins[3][t]);
    }
}

// ---------------- NTN + histogram concat + fc1 + fc2 head ----------------
__global__ void final_kernel(const float* __restrict__ e1, const float* __restrict__ e2,
                             const float* __restrict__ ntnW, const float* __restrict__ ntnV,
                             const float* __restrict__ ntnb, const float* __restrict__ counts,
                             const float* __restrict__ fc1W, const float* __restrict__ fc1b,
                             const float* __restrict__ fc2W, const float* __restrict__ fc2b,
                             float* __restrict__ out) {
    int b = blockIdx.x;
    int t = threadIdx.x;
    __shared__ float a1[32], a2[32], red[256], z[32], u[16];
    if (t < 32) a1[t] = e1[b * 32 + t];
    else if (t < 64) a2[t - 32] = e2[b * 32 + t - 32];
    __syncthreads();
    int tt = t >> 4, g = t & 15;
    float p = 0.f;
#pragma unroll
    for (int ii = 0; ii < 2; ii++) {
        int i = g + 16 * ii;
        float d = 0.f;
        const float* wr = ntnW + (tt * 32 + i) * 32;
        for (int j = 0; j < 32; j++) d += wr[j] * a2[j];
        p += a1[i] * d;
    }
    red[t] = p;
    __syncthreads();
    if (t < 16) {
        float s = 0.f;
        for (int g2 = 0; g2 < 16; g2++) s += red[t * 16 + g2];
        float lin = ntnb[t];
        for (int i = 0; i < 32; i++) lin += ntnV[t * 64 + i] * a1[i];
        for (int i = 0; i < 32; i++) lin += ntnV[t * 64 + 32 + i] * a2[i];
        z[t] = fmaxf(s + lin, 0.f);
    } else if (t < 32) {
        float tot = 0.f;
        for (int i = 0; i < BINS; i++) tot += counts[i];
        z[t] = counts[t - 16] / tot;
    }
    __syncthreads();
    if (t < 16) {
        float a = fc1b[t];
        for (int i = 0; i < 32; i++) a += fc1W[t * 32 + i] * z[i];
        u[t] = fmaxf(a, 0.f);
    }
    __syncthreads();
    if (t == 0) {
        float a = fc2b[0];
        for (int i = 0; i < 16; i++) a += fc2W[i] * u[i];
        out[b] = 1.f / (1.f + expf(-a));
    }
}

extern "C" void kernel_launch(void* const* d_in, const int* in_sizes, int n_in,
                              void* d_out, int out_size, void* d_ws, size_t ws_size,
                              hipStream_t stream) {
    const float* xq   = (const float*)d_in[0];
    const float* xc   = (const float*)d_in[1];
    const int*   eq   = (const int*)d_in[2];
    const int*   ec   = (const int*)d_in[3];
    const float* W1   = (const float*)d_in[4];
    const float* b1   = (const float*)d_in[5];
    const float* W2   = (const float*)d_in[6];
    const float* b2   = (const float*)d_in[7];
    const float* W3   = (const float*)d_in[8];
    const float* b3   = (const float*)d_in[9];
    const float* Watt = (const float*)d_in[10];
    const float* ntnW = (const float*)d_in[11];
    const float* ntnV = (const float*)d_in[12];
    const float* ntnb = (const float*)d_in[13];
    const float* fc1W = (const float*)d_in[14];
    const float* fc1b = (const float*)d_in[15];
    const float* fc2W = (const float*)d_in[16];
    const float* fc2b = (const float*)d_in[17];
    float* out = (float*)d_out;
    float* ws  = (float*)d_ws;

    // ---- workspace layout (float indices), round-0 proven footprint ----
    float* O3   = ws;                           // 2*B*N*32  = 2097152
    float* e12  = O3 + 2097152;                 // 2*B*32    = 8192
    float* bmin = e12 + 8192;                   // 2048 (unused, layout keep)
    float* bmax = bmin + 2048;                  // 2048 (unused, layout keep)
    unsigned int* lohiE = (unsigned int*)(bmax + 2048);  // 2 encoded uints
    float* cntw = (float*)(lohiE + 2);          // 16
    int*   off  = (int*)(ws + 2109504);         // 2B*257 = 65792
    int*   srcs = off + 65792;                  // 2B*E = 524288
    float* wts  = (float*)(srcs + 524288);      // 524288
    float* O1   = ws + 3223872;                 // 2*B*N*128 = 8388608
    float* O2   = O1 + 8388608;                 // 2*B*N*64  = 4194304

    float* O3Q = O3;
    float* O3C = O3 + (size_t)BB * NN * 32;
    float* e1w = e12;
    float* e2w = e12 + BB * 32;
    (void)bmin; (void)bmax;

    csr_kernel<<<2 * BB, 256, 0, stream>>>(eq, ec, off, srcs, wts, lohiE, cntw);

    gcn_fused8<128, 128, true, 1><<<4 * 2 * BB, 512, 0, stream>>>(
        xq, xc, W1, b1, off, srcs, wts, O1);
    gcn_fused8<128, 64, true, 1><<<2 * 2 * BB, 512, 0, stream>>>(
        O1, O1 + (size_t)BB * NN * 128, W2, b2, off, srcs, wts, O2);
    gcn_fused8<64, 32, false, 2><<<2 * 2 * BB, 512, 0, stream>>>(
        O2, O2 + (size_t)BB * NN * 64, W3, b3, off, srcs, wts, O3);

    attpool_kernel<<<2 * BB, 256, 0, stream>>>(O3, Watt, e12);

    pairdot_minmax<<<BB * 4, 256, 0, stream>>>(O3Q, O3C, lohiE);
    pairdot_hist<<<BB * 4, 256, 0, stream>>>(O3Q, O3C, lohiE, cntw);

    final_kernel<<<BB, 256, 0, stream>>>(e1w, e2w, ntnW, ntnV, ntnb, cntw,
                                         fc1W, fc1b, fc2W, fc2b, out);
}